// Round 9
// baseline (559.854 us; speedup 1.0000x reference)
//
#include <hip/hip_runtime.h>
#include <hip/hip_bf16.h>
#include <math.h>

typedef __bf16 BF16;
typedef __attribute__((ext_vector_type(8))) __bf16 bf16x8;
typedef __attribute__((ext_vector_type(4))) float f32x4;

__device__ __forceinline__ void gld_lds16(const void* g, void* l) {
    __builtin_amdgcn_global_load_lds(
        (__attribute__((address_space(1))) void*)(const void*)g,
        (__attribute__((address_space(3))) void*)l, 16, 0, 0);
}

// Counted vmcnt WITHOUT memory clobber: a "memory" clobber makes LLVM insert
// conservative waitcnt drains, defeating the counted-vmcnt pipeline (r3-r5's
// 32% plateau). Ordering is pinned by sched_barrier(0) (compile-time only).
template <int N> __device__ __forceinline__ void vmwait() {
    asm volatile("s_waitcnt vmcnt(%0)" :: "i"(N));
}

__device__ __forceinline__ void SBAR() {
    __builtin_amdgcn_sched_barrier(0);
    __builtin_amdgcn_s_barrier();
    __builtin_amdgcn_sched_barrier(0);
}

// ---------------- LayerNorm (fp32 in -> bf16 out), row = 2048 ----------------
__global__ __launch_bounds__(256) void lnorm(const float* __restrict__ x,
                                             const float* __restrict__ w,
                                             BF16* __restrict__ out) {
    const int row = blockIdx.x, tid = threadIdx.x;
    const float* xr = x + (size_t)row * 2048;
    float4 a = *(const float4*)(xr + tid * 8);
    float4 b = *(const float4*)(xr + tid * 8 + 4);
    float s1 = a.x + a.y + a.z + a.w + b.x + b.y + b.z + b.w;
    float s2 = a.x*a.x + a.y*a.y + a.z*a.z + a.w*a.w +
               b.x*b.x + b.y*b.y + b.z*b.z + b.w*b.w;
    #pragma unroll
    for (int off = 32; off; off >>= 1) {
        s1 += __shfl_xor(s1, off);
        s2 += __shfl_xor(s2, off);
    }
    __shared__ float red[8];
    const int l = tid & 63, wv = tid >> 6;
    if (l == 0) { red[wv] = s1; red[4 + wv] = s2; }
    __syncthreads();
    s1 = red[0] + red[1] + red[2] + red[3];
    s2 = red[4] + red[5] + red[6] + red[7];
    const float mean = s1 * (1.0f / 2048.0f);
    const float var  = s2 * (1.0f / 2048.0f) - mean * mean;
    const float rstd = rsqrtf(var + 1e-5f);
    float4 wa = *(const float4*)(w + tid * 8);
    float4 wb = *(const float4*)(w + tid * 8 + 4);
    bf16x8 o;
    o[0] = (BF16)((a.x - mean) * rstd * wa.x);
    o[1] = (BF16)((a.y - mean) * rstd * wa.y);
    o[2] = (BF16)((a.z - mean) * rstd * wa.z);
    o[3] = (BF16)((a.w - mean) * rstd * wa.w);
    o[4] = (BF16)((b.x - mean) * rstd * wb.x);
    o[5] = (BF16)((b.y - mean) * rstd * wb.y);
    o[6] = (BF16)((b.z - mean) * rstd * wb.z);
    o[7] = (BF16)((b.w - mean) * rstd * wb.w);
    *(bf16x8*)(out + (size_t)row * 2048 + tid * 8) = o;
}

// ------------- fp32 [K][N] -> bf16 [N][K] transposed convert -----------------
__global__ __launch_bounds__(256) void wtrans(const float* __restrict__ W,
                                              BF16* __restrict__ Wt,
                                              int K, int N) {
    __shared__ BF16 tile[32][33];
    const int n0 = blockIdx.x * 32, k0 = blockIdx.y * 32;
    const int tx = threadIdx.x, ty = threadIdx.y;
    #pragma unroll
    for (int i = 0; i < 4; i++)
        tile[ty + 8 * i][tx] = (BF16)W[(size_t)(k0 + ty + 8 * i) * N + n0 + tx];
    __syncthreads();
    #pragma unroll
    for (int i = 0; i < 4; i++)
        Wt[(size_t)(n0 + ty + 8 * i) * K + k0 + tx] = tile[tx][ty + 8 * i];
}

// --------- V slice of qkv (bf16 [B,T,3C]) -> vT bf16 [B*H][128][2048] ---------
__global__ __launch_bounds__(256) void vtrans(const BF16* __restrict__ qkv,
                                              BF16* __restrict__ vT) {
    __shared__ BF16 tile[32][33];
    const int t0 = blockIdx.x * 32, d0 = blockIdx.y * 32, bh = blockIdx.z;
    const int b = bh >> 4, h = bh & 15;
    const int tx = threadIdx.x, ty = threadIdx.y;
    const BF16* src = qkv + (size_t)b * 2048 * 6144 + 4096 + h * 128;
    #pragma unroll
    for (int i = 0; i < 4; i++)
        tile[ty + 8 * i][tx] = src[(size_t)(t0 + ty + 8 * i) * 6144 + d0 + tx];
    __syncthreads();
    BF16* dst = vT + (size_t)bh * 128 * 2048;
    #pragma unroll
    for (int i = 0; i < 4; i++)
        dst[(size_t)(d0 + ty + 8 * i) * 2048 + t0 + tx] = tile[tx][ty + 8 * i];
}

// ============ GEMM: C[M,N] = A[M,K] * Bt[N,K]^T, BM=256, BK=64 ==============
// 8 waves (2M x 4N), wave tile 128 x (BN/4). LDS per K-tile buffer stored as
// [2 kk][rows][32 elems]: 64B rows, 4 slots of 16B, slot XOR (r>>1)&3 ->
// 2 lanes/bank-group on reads = conflict-FREE (r3-verified layout).
// A buffer = 256 rows * 64 B = 32 KB -> buffer stride 32768 (r8 fix: was
// 65536, which made A buf1 overlap B buf0 at smem+65536 -> absmax 945).

#define STA(SI, KK, TS) do { \
    _Pragma("unroll") \
    for (int j_ = 0; j_ < 2; ++j_) { \
        const int r_ = j_ * 128 + (tid >> 2); \
        const int sl_ = (tid & 3) ^ ((r_ >> 1) & 3); \
        gld_lds16(A + (size_t)(m0 + r_) * K + (TS) * 64 + (KK) * 32 + sl_ * 8, \
                  Ab + (SI) * 32768 + (KK) * 16384 + j_ * 8192 + w * 1024); \
    } \
} while (0)

#define STB(SI, KK, TS) do { \
    _Pragma("unroll") \
    for (int j_ = 0; j_ < LBU; ++j_) { \
        const int r_ = j_ * 128 + (tid >> 2); \
        const int sl_ = (tid & 3) ^ ((r_ >> 1) & 3); \
        gld_lds16(Bt + (size_t)(n0 + r_) * K + (TS) * 64 + (KK) * 32 + sl_ * 8, \
                  Bb + (SI) * BBUF + (KK) * (BN * 64) + j_ * 8192 + w * 1024); \
    } \
} while (0)

#define LDA(BI, MH, M_, KK) \
    (*(const bf16x8*)(Ab + (BI) * 32768 + (KK) * 16384 + \
        ((MH) * 128 + wm * 64 + (M_) * 16 + c) * 64 + ((g ^ fa) << 4)))

#define LDB(BI, N_, KK) \
    (*(const bf16x8*)(Bb + (BI) * BBUF + (KK) * (BN * 64) + \
        (wn * (BN / 4) + (N_) * 16 + c) * 64 + ((g ^ fa) << 4)))

#define MFMA_CL(MH) do { \
    __builtin_amdgcn_s_setprio(1); \
    _Pragma("unroll") \
    for (int m_ = 0; m_ < 4; ++m_) \
      _Pragma("unroll") \
      for (int n_ = 0; n_ < NR; ++n_) \
        acc[(MH) * 4 + m_][n_] = __builtin_amdgcn_mfma_f32_16x16x32_bf16( \
            af[m_], bfr[n_], acc[(MH) * 4 + m_][n_], 0, 0, 0); \
    __builtin_amdgcn_s_setprio(0); \
} while (0)

// Steady-state per-thread FIFO ledger (A-unit=2 loads, B-unit=LBU):
// enter: {Bk1(T),Ak1(T)} = LBU+2 in flight.
// p0 +Bk0(T+1); p1 +Ak0(T+1), end-p1 wait vmcnt(LBU+2) drains Bk1,Ak1(T)
//   (issued 2-3 phases earlier). p2 +Bk1(T+1); p3 +Ak1(T+1), end-p3 wait
//   vmcnt(LBU+2) drains Bk0,Ak0(T+1) (slack 3 and 2 phases).
#define GBODY(BI, T, ST) do { \
    bf16x8 af[4], bfr[NR]; \
    _Pragma("unroll") for (int n_ = 0; n_ < NR; ++n_) bfr[n_] = LDB(BI, n_, 0); \
    _Pragma("unroll") for (int m_ = 0; m_ < 4; ++m_) af[m_] = LDA(BI, 0, m_, 0); \
    if (ST) STB((BI) ^ 1, 0, (T) + 1); \
    SBAR(); \
    MFMA_CL(0); \
    SBAR(); \
    _Pragma("unroll") for (int m_ = 0; m_ < 4; ++m_) af[m_] = LDA(BI, 1, m_, 0); \
    if (ST) STA((BI) ^ 1, 0, (T) + 1); \
    SBAR(); \
    MFMA_CL(1); \
    if (ST) vmwait<LBU + 2>(); else vmwait<0>(); \
    SBAR(); \
    _Pragma("unroll") for (int n_ = 0; n_ < NR; ++n_) bfr[n_] = LDB(BI, n_, 1); \
    _Pragma("unroll") for (int m_ = 0; m_ < 4; ++m_) af[m_] = LDA(BI, 0, m_, 1); \
    if (ST) STB((BI) ^ 1, 1, (T) + 1); \
    SBAR(); \
    MFMA_CL(0); \
    SBAR(); \
    _Pragma("unroll") for (int m_ = 0; m_ < 4; ++m_) af[m_] = LDA(BI, 1, m_, 1); \
    if (ST) STA((BI) ^ 1, 1, (T) + 1); \
    SBAR(); \
    MFMA_CL(1); \
    if (ST) vmwait<LBU + 2>(); \
    SBAR(); \
} while (0)

template <int MODE, int BN>
__global__ __launch_bounds__(512) void gemmT(const BF16* __restrict__ A,
                                             const BF16* __restrict__ Bt,
                                             void* __restrict__ out,
                                             const float* __restrict__ resid,
                                             int M, int N, int K) {
    constexpr int NR   = BN / 64;      // n-frags per wave: 4 or 2
    constexpr int LBU  = BN / 128;     // loads per B stage unit: 2 or 1
    constexpr int BBUF = BN * 128;     // B buffer bytes (2 kk units)
    (void)M;

    extern __shared__ char smem[];
    char* const Ab = smem;             // 2 bufs x 32 KB = [0, 65536)
    char* const Bb = smem + 65536;     // 2 bufs x (BN*128) B

    const int tid = threadIdx.x, l = tid & 63, w = tid >> 6;
    const int wm = w >> 2, wn = w & 3;
    const int g = l >> 4, c = l & 15;
    const int fa = (c >> 1) & 3;       // read-side slot XOR == (r>>1)&3

    const int NBX = N / BN;
    const int cpx = (int)gridDim.x >> 3;
    const int bid = (int)blockIdx.x;
    const int wg  = (bid & 7) * cpx + (bid >> 3);
    const int m0 = (wg / NBX) * 256, n0 = (wg % NBX) * BN;

    f32x4 acc[8][NR] = {};

    // prologue: stage tile 0 (Bk0, Ak0, Bk1, Ak1); wait for first half
    STB(0, 0, 0); STA(0, 0, 0); STB(0, 1, 0); STA(0, 1, 0);
    vmwait<LBU + 2>();
    SBAR();

    const int NT = K >> 6;             // even for all our K (2048/8192)
    for (int t = 0; t < NT - 2; t += 2) {
        GBODY(0, t, true);
        GBODY(1, t + 1, true);
    }
    GBODY(0, NT - 2, true);
    GBODY(1, NT - 1, false);

    #pragma unroll
    for (int mi = 0; mi < 8; mi++)
      #pragma unroll
      for (int ni = 0; ni < NR; ni++)
        #pragma unroll
        for (int j = 0; j < 4; j++) {
            const int row = m0 + (mi >> 2) * 128 + wm * 64 + (mi & 3) * 16 + g * 4 + j;
            const int col = n0 + wn * (BN / 4) + ni * 16 + c;
            const float v = acc[mi][ni][j];
            const size_t idx = (size_t)row * N + col;
            if (MODE == 0) {
                ((BF16*)out)[idx] = (BF16)v;
            } else if (MODE == 1) {
                const float t2 = v + 0.044715f * v * v * v;
                const float s = 1.0f / (1.0f + __expf(-1.5957691216057308f * t2));
                ((BF16*)out)[idx] = (BF16)(v * s);
            } else {
                ((float*)out)[idx] = resid[idx] + v;
            }
        }
}

// ------------------------- causal flash attention ----------------------------
// 512 uniform blocks: block = (pair, bh), processes qb=pair then qb=31-pair
// (exactly 33 K/V-tiles). Double-buffered K/V staging, counted vmcnt(8),
// clobber-free sync. XCD-chunked mapping: 64 consecutive wg per XCD.
__global__ __launch_bounds__(256) void attn(const BF16* __restrict__ qkv,
                                            const BF16* __restrict__ vT,
                                            const float* __restrict__ x,
                                            float* __restrict__ x2) {
    __shared__ BF16 Ks[2][64 * 128];   // [key][d], swizzled rows (256 B)
    __shared__ BF16 Vs[2][128 * 64];   // [d][key], swizzled rows (128 B)
    __shared__ BF16 Ps[4][16 * 72];    // per-wave P [q][key], pad 64->72
    const int tid = threadIdx.x, l = tid & 63, w = tid >> 6;
    const int g = l >> 4, c = l & 15;
    const int bid = (int)blockIdx.x;
    const int wg = (bid & 7) * 64 + (bid >> 3);   // XCD chunking
    const int pair = wg & 15, bh = wg >> 4;
    const int b = bh >> 4, h = bh & 15;
    const int xr = (c & 7) << 4;       // read-side XOR (row = *16 + c)

    const BF16* qbase = qkv + (size_t)b * 2048 * 6144 + h * 128;
    const char* kbase = (const char*)(qbase + 2048);
    const char* vbase = (const char*)(vT + (size_t)bh * 128 * 2048);

    auto STAGE = [&](int bb, int k0) {
        #pragma unroll
        for (int s = 0; s < 4; ++s) {
            const int rK = (w * 4 + s) * 4 + (l >> 4);
            const int cK = ((l & 15) * 16) ^ ((rK & 7) << 4);
            gld_lds16(kbase + (size_t)(k0 + rK) * 12288 + cK,
                      &Ks[bb][(w * 4 + s) * 512]);
            const int rV = (w * 4 + s) * 8 + (l >> 3);
            const int cV = ((l & 7) * 16) ^ ((rV & 7) << 4);
            gld_lds16(vbase + (size_t)rV * 4096 + (size_t)k0 * 2 + cV,
                      &Vs[bb][(w * 4 + s) * 512]);
        }
    };

    const float scale = 0.08838834764831845f;  // 1/sqrt(128)

    #pragma unroll 1
    for (int seg = 0; seg < 2; ++seg) {
        const int qb = seg ? 31 - pair : pair;
        const int q0 = qb * 64;

        bf16x8 qf[4];
        {
            const BF16* qrow = qbase + (size_t)(q0 + w * 16 + c) * 6144 + g * 8;
            #pragma unroll
            for (int kc = 0; kc < 4; kc++)
                qf[kc] = *(const bf16x8*)(qrow + kc * 32);
        }
        float m[4]    = {-1e30f, -1e30f, -1e30f, -1e30f};
        float lsum[4] = {0.f, 0.f, 0.f, 0.f};
        f32x4 O[8] = {};

        STAGE(0, 0);
        #pragma unroll 1
        for (int kt = 0; kt <= qb; ++kt) {
            if (kt < qb) { STAGE((kt + 1) & 1, (kt + 1) * 64); vmwait<8>(); }
            else vmwait<0>();
            SBAR();
            const char* KsB = (const char*)Ks[kt & 1];
            const char* VsB = (const char*)Vs[kt & 1];

            f32x4 s4[4] = {};
            #pragma unroll
            for (int ni = 0; ni < 4; ni++)
                #pragma unroll
                for (int kc = 0; kc < 4; kc++) {
                    const bf16x8 kf = *(const bf16x8*)(KsB +
                        (ni * 16 + c) * 256 + ((kc * 64 + g * 16) ^ xr));
                    s4[ni] = __builtin_amdgcn_mfma_f32_16x16x32_bf16(
                        qf[kc], kf, s4[ni], 0, 0, 0);
                }

            const bool maskt = (kt == qb);
            float sv[4][4];
            #pragma unroll
            for (int ni = 0; ni < 4; ni++)
                #pragma unroll
                for (int j = 0; j < 4; j++) {
                    const float v = s4[ni][j] * scale;
                    sv[ni][j] = (!maskt || (ni * 16 + c <= w * 16 + g * 4 + j))
                              ? v : -1e30f;
                }

            float sf[4];
            #pragma unroll
            for (int j = 0; j < 4; j++) {
                float tm = fmaxf(fmaxf(sv[0][j], sv[1][j]),
                                 fmaxf(sv[2][j], sv[3][j]));
                tm = fmaxf(tm, __shfl_xor(tm, 1));
                tm = fmaxf(tm, __shfl_xor(tm, 2));
                tm = fmaxf(tm, __shfl_xor(tm, 4));
                tm = fmaxf(tm, __shfl_xor(tm, 8));
                const float mn = fmaxf(m[j], tm);
                sf[j] = __expf(m[j] - mn);
                m[j] = mn;
            }

            float rs[4] = {0.f, 0.f, 0.f, 0.f};
            #pragma unroll
            for (int ni = 0; ni < 4; ni++)
                #pragma unroll
                for (int j = 0; j < 4; j++) {
                    const float p = __expf(sv[ni][j] - m[j]);
                    rs[j] += p;
                    Ps[w][(g * 4 + j) * 72 + ni * 16 + c] = (BF16)p;
                }
            #pragma unroll
            for (int j = 0; j < 4; j++) {
                float t = rs[j];
                t += __shfl_xor(t, 1);
                t += __shfl_xor(t, 2);
                t += __shfl_xor(t, 4);
                t += __shfl_xor(t, 8);
                lsum[j] = lsum[j] * sf[j] + t;
            }
            #pragma unroll
            for (int dn = 0; dn < 8; dn++)
                #pragma unroll
                for (int j = 0; j < 4; j++) O[dn][j] *= sf[j];

            bf16x8 pa[2];
            #pragma unroll
            for (int ks = 0; ks < 2; ks++)
                pa[ks] = *(const bf16x8*)((const char*)Ps[w] +
                             c * 144 + ks * 64 + g * 16);
            #pragma unroll
            for (int dn = 0; dn < 8; dn++)
                #pragma unroll
                for (int ks = 0; ks < 2; ks++) {
                    const bf16x8 vf = *(const bf16x8*)(VsB +
                        (dn * 16 + c) * 128 + ((ks * 64 + g * 16) ^ xr));
                    O[dn] = __builtin_amdgcn_mfma_f32_16x16x32_bf16(
                        pa[ks], vf, O[dn], 0, 0, 0);
                }
            SBAR();
        }

        float inv[4];
        #pragma unroll
        for (int j = 0; j < 4; j++) inv[j] = 1.0f / lsum[j];
        #pragma unroll
        for (int dn = 0; dn < 8; dn++)
            #pragma unroll
            for (int j = 0; j < 4; j++) {
                const int t   = q0 + w * 16 + g * 4 + j;
                const int col = h * 128 + dn * 16 + c;
                const size_t idx = ((size_t)b * 2048 + t) * 2048 + col;
                x2[idx] = x[idx] + O[dn][j] * inv[j];
            }
    }
}

// -----------------------------------------------------------------------------
extern "C" void kernel_launch(void* const* d_in, const int* in_sizes, int n_in,
                              void* d_out, int out_size, void* d_ws, size_t ws_size,
                              hipStream_t stream) {
    const float* x     = (const float*)d_in[0];
    const float* w_qkv = (const float*)d_in[1];
    const float* w1    = (const float*)d_in[2];
    const float* w2    = (const float*)d_in[3];
    const float* ln_w  = (const float*)d_in[4];
    float* out = (float*)d_out;

    char* ws = (char*)d_ws;
    BF16* h_buf = (BF16*)ws;  ws += (size_t)4096 * 2048 * 2;
    BF16* qkvb  = (BF16*)ws;  ws += (size_t)4096 * 6144 * 2;
    BF16* vTb   = (BF16*)ws;  ws += (size_t)32 * 128 * 2048 * 2;
    BF16* wqkvT = (BF16*)ws;  ws += (size_t)6144 * 2048 * 2;
    BF16* w1T   = (BF16*)ws;  ws += (size_t)8192 * 2048 * 2;
    BF16* w2T   = (BF16*)ws;  ws += (size_t)2048 * 8192 * 2;
    BF16* mlp1  = (BF16*)ws;  ws += (size_t)4096 * 8192 * 2;

    hipFuncSetAttribute((const void*)&gemmT<0, 256>,
                        hipFuncAttributeMaxDynamicSharedMemorySize, 131072);
    hipFuncSetAttribute((const void*)&gemmT<1, 256>,
                        hipFuncAttributeMaxDynamicSharedMemorySize, 131072);
    hipFuncSetAttribute((const void*)&gemmT<2, 128>,
                        hipFuncAttributeMaxDynamicSharedMemorySize, 98304);

    // ---- attention branch ----
    lnorm<<<4096, 256, 0, stream>>>(x, ln_w, h_buf);
    wtrans<<<dim3(192, 64), dim3(32, 8), 0, stream>>>(w_qkv, wqkvT, 2048, 6144);
    gemmT<0, 256><<<384, 512, 131072, stream>>>(
        h_buf, wqkvT, qkvb, nullptr, 4096, 6144, 2048);
    vtrans<<<dim3(64, 4, 32), dim3(32, 8), 0, stream>>>(qkvb, vTb);
    attn<<<512, 256, 0, stream>>>(qkvb, vTb, x, out);  // out = x2

    // ---- MLP branch ----
    lnorm<<<4096, 256, 0, stream>>>(out, ln_w, h_buf);
    wtrans<<<dim3(256, 64), dim3(32, 8), 0, stream>>>(w1, w1T, 2048, 8192);
    gemmT<1, 256><<<512, 512, 131072, stream>>>(
        h_buf, w1T, mlp1, nullptr, 4096, 8192, 2048);
    wtrans<<<dim3(64, 256), dim3(32, 8), 0, stream>>>(w2, w2T, 8192, 2048);
    gemmT<2, 128><<<256, 512, 98304, stream>>>(
        mlp1, w2T, out, out, 4096, 2048, 8192);
}

// Round 10
// 549.836 us; speedup vs baseline: 1.0182x; 1.0182x over previous
//
#include <hip/hip_runtime.h>
#include <hip/hip_bf16.h>
#include <math.h>

typedef __bf16 BF16;
typedef __attribute__((ext_vector_type(8))) __bf16 bf16x8;
typedef __attribute__((ext_vector_type(4))) float f32x4;

__device__ __forceinline__ void gld_lds16(const void* g, void* l) {
    __builtin_amdgcn_global_load_lds(
        (__attribute__((address_space(1))) void*)(const void*)g,
        (__attribute__((address_space(3))) void*)l, 16, 0, 0);
}

// clobber-free counted vmcnt (no "memory" clobber -> no compiler drain)
template <int N> __device__ __forceinline__ void vmwait() {
    asm volatile("s_waitcnt vmcnt(%0)" :: "i"(N));
}

// ---------------- LayerNorm (fp32 in -> bf16 out), row = 2048 ----------------
__global__ __launch_bounds__(256) void lnorm(const float* __restrict__ x,
                                             const float* __restrict__ w,
                                             BF16* __restrict__ out) {
    const int row = blockIdx.x, tid = threadIdx.x;
    const float* xr = x + (size_t)row * 2048;
    float4 a = *(const float4*)(xr + tid * 8);
    float4 b = *(const float4*)(xr + tid * 8 + 4);
    float s1 = a.x + a.y + a.z + a.w + b.x + b.y + b.z + b.w;
    float s2 = a.x*a.x + a.y*a.y + a.z*a.z + a.w*a.w +
               b.x*b.x + b.y*b.y + b.z*b.z + b.w*b.w;
    #pragma unroll
    for (int off = 32; off; off >>= 1) {
        s1 += __shfl_xor(s1, off);
        s2 += __shfl_xor(s2, off);
    }
    __shared__ float red[8];
    const int l = tid & 63, wv = tid >> 6;
    if (l == 0) { red[wv] = s1; red[4 + wv] = s2; }
    __syncthreads();
    s1 = red[0] + red[1] + red[2] + red[3];
    s2 = red[4] + red[5] + red[6] + red[7];
    const float mean = s1 * (1.0f / 2048.0f);
    const float var  = s2 * (1.0f / 2048.0f) - mean * mean;
    const float rstd = rsqrtf(var + 1e-5f);
    float4 wa = *(const float4*)(w + tid * 8);
    float4 wb = *(const float4*)(w + tid * 8 + 4);
    bf16x8 o;
    o[0] = (BF16)((a.x - mean) * rstd * wa.x);
    o[1] = (BF16)((a.y - mean) * rstd * wa.y);
    o[2] = (BF16)((a.z - mean) * rstd * wa.z);
    o[3] = (BF16)((a.w - mean) * rstd * wa.w);
    o[4] = (BF16)((b.x - mean) * rstd * wb.x);
    o[5] = (BF16)((b.y - mean) * rstd * wb.y);
    o[6] = (BF16)((b.z - mean) * rstd * wb.z);
    o[7] = (BF16)((b.w - mean) * rstd * wb.w);
    *(bf16x8*)(out + (size_t)row * 2048 + tid * 8) = o;
}

// ------------- fp32 [K][N] -> bf16 [N][K] transposed convert -----------------
__global__ __launch_bounds__(256) void wtrans(const float* __restrict__ W,
                                              BF16* __restrict__ Wt,
                                              int K, int N) {
    __shared__ BF16 tile[32][33];
    const int n0 = blockIdx.x * 32, k0 = blockIdx.y * 32;
    const int tx = threadIdx.x, ty = threadIdx.y;
    #pragma unroll
    for (int i = 0; i < 4; i++)
        tile[ty + 8 * i][tx] = (BF16)W[(size_t)(k0 + ty + 8 * i) * N + n0 + tx];
    __syncthreads();
    #pragma unroll
    for (int i = 0; i < 4; i++)
        Wt[(size_t)(n0 + ty + 8 * i) * K + k0 + tx] = tile[tx][ty + 8 * i];
}

// --------- V slice of qkv (bf16 [B,T,3C]) -> vT bf16 [B*H][128][2048] ---------
__global__ __launch_bounds__(256) void vtrans(const BF16* __restrict__ qkv,
                                              BF16* __restrict__ vT) {
    __shared__ BF16 tile[32][33];
    const int t0 = blockIdx.x * 32, d0 = blockIdx.y * 32, bh = blockIdx.z;
    const int b = bh >> 4, h = bh & 15;
    const int tx = threadIdx.x, ty = threadIdx.y;
    const BF16* src = qkv + (size_t)b * 2048 * 6144 + 4096 + h * 128;
    #pragma unroll
    for (int i = 0; i < 4; i++)
        tile[ty + 8 * i][tx] = src[(size_t)(t0 + ty + 8 * i) * 6144 + d0 + tx];
    __syncthreads();
    BF16* dst = vT + (size_t)bh * 128 * 2048;
    #pragma unroll
    for (int i = 0; i < 4; i++)
        dst[(size_t)(d0 + ty + 8 * i) * 2048 + t0 + tx] = tile[tx][ty + 8 * i];
}

// ====== GEMM: C[M,N] = A[M,K]*Bt[N,K]^T, BK=32, 4-deep buffer rotation ======
// 8 waves (2M x 4N), BN=256 (wave cols 64). One barrier + one counted vmcnt
// per K-tile; no intra-body fences (compiler interleaves ds_read/MFMA).
// LDS buf = A(BM x 32 elems, 64B rows) + B(256 x 32), slot XOR (r>>1)&3,
// 0-conflict (r9-verified). Body(t): read buf t&3, stage t+3 -> (t+3)&3,
// vmcnt leaves {t+2,t+3} in flight (tile t+1 staged 2 bodies ago = ample).

#define STA(SI, TS) do { \
    _Pragma("unroll") \
    for (int j_ = 0; j_ < LA; ++j_) { \
        const int r_ = j_ * 128 + (tid >> 2); \
        const int sl_ = (tid & 3) ^ ((r_ >> 1) & 3); \
        gld_lds16(A + (size_t)(m0 + r_) * K + (TS) * 32 + sl_ * 8, \
                  Ab + (SI) * ABUF + j_ * 8192 + w * 1024); \
    } \
} while (0)

#define STB(SI, TS) do { \
    _Pragma("unroll") \
    for (int j_ = 0; j_ < 2; ++j_) { \
        const int r_ = j_ * 128 + (tid >> 2); \
        const int sl_ = (tid & 3) ^ ((r_ >> 1) & 3); \
        gld_lds16(Bt + (size_t)(n0 + r_) * K + (TS) * 32 + sl_ * 8, \
                  Bb + (SI) * 16384 + j_ * 8192 + w * 1024); \
    } \
} while (0)

#define LDA(BI, M_) \
    (*(const bf16x8*)(Ab + (BI) * ABUF + \
        (wm * (BM / 2) + (M_) * 16 + c) * 64 + ((g ^ fa) << 4)))

#define LDB(BI, N_) \
    (*(const bf16x8*)(Bb + (BI) * 16384 + \
        (wn * 64 + (N_) * 16 + c) * 64 + ((g ^ fa) << 4)))

#define GB(BI, T, DS, VW) do { \
    bf16x8 af[MR], bfr[4]; \
    _Pragma("unroll") for (int n_ = 0; n_ < 4; ++n_) bfr[n_] = LDB(BI, n_); \
    _Pragma("unroll") for (int m_ = 0; m_ < MR; ++m_) af[m_] = LDA(BI, m_); \
    if (DS) { STB(((BI) + 3) & 3, (T) + 3); STA(((BI) + 3) & 3, (T) + 3); } \
    _Pragma("unroll") \
    for (int m_ = 0; m_ < MR; ++m_) \
      _Pragma("unroll") \
      for (int n_ = 0; n_ < 4; ++n_) \
        acc[m_][n_] = __builtin_amdgcn_mfma_f32_16x16x32_bf16( \
            af[m_], bfr[n_], acc[m_][n_], 0, 0, 0); \
    vmwait<(VW)>(); \
    __builtin_amdgcn_s_barrier(); \
    __builtin_amdgcn_sched_barrier(0); \
} while (0)

template <int MODE, int BM>
__global__ __launch_bounds__(512) void gemmN(const BF16* __restrict__ A,
                                             const BF16* __restrict__ Bt,
                                             void* __restrict__ out,
                                             const float* __restrict__ resid,
                                             int M, int N, int K) {
    constexpr int MR   = BM / 32;        // m-frags per wave: 8 or 4
    constexpr int LA   = BM / 128;       // A stage loads/thread: 2 or 1
    constexpr int LPT  = LA + 2;         // loads per tile per thread
    constexpr int ABUF = BM * 64;        // A buffer bytes
    (void)M;

    extern __shared__ char smem[];
    char* const Ab = smem;               // 4 bufs x ABUF
    char* const Bb = smem + 4 * ABUF;    // 4 bufs x 16 KB

    const int tid = threadIdx.x, l = tid & 63, w = tid >> 6;
    const int wm = w >> 2, wn = w & 3;
    const int g = l >> 4, c = l & 15;
    const int fa = (c >> 1) & 3;

    const int NBX = N >> 8;              // BN = 256
    const int cpx = (int)gridDim.x >> 3;
    const int bid = (int)blockIdx.x;
    const int wg  = (bid & 7) * cpx + (bid >> 3);
    const int m0 = (wg / NBX) * BM, n0 = (wg % NBX) * 256;

    f32x4 acc[MR][4] = {};

    // prologue: stage tiles 0,1,2; drain tile 0; sync
    STB(0, 0); STA(0, 0);
    STB(1, 1); STA(1, 1);
    STB(2, 2); STA(2, 2);
    vmwait<2 * LPT>();
    __builtin_amdgcn_s_barrier();
    __builtin_amdgcn_sched_barrier(0);

    const int NT = K >> 5;               // 64 / 64 / 256 (all %4==0, >=8)
    for (int t = 0; t < NT - 4; t += 4) {
        GB(0, t,     1, 2 * LPT);
        GB(1, t + 1, 1, 2 * LPT);
        GB(2, t + 2, 1, 2 * LPT);
        GB(3, t + 3, 1, 2 * LPT);
    }
    GB(0, NT - 4, 1, 2 * LPT);
    GB(1, NT - 3, 0, LPT);
    GB(2, NT - 2, 0, 0);
    GB(3, NT - 1, 0, 0);

    #pragma unroll
    for (int mi = 0; mi < MR; mi++)
      #pragma unroll
      for (int ni = 0; ni < 4; ni++)
        #pragma unroll
        for (int j = 0; j < 4; j++) {
            const int row = m0 + wm * (BM / 2) + mi * 16 + g * 4 + j;
            const int col = n0 + wn * 64 + ni * 16 + c;
            const float v = acc[mi][ni][j];
            const size_t idx = (size_t)row * N + col;
            if (MODE == 0) {
                ((BF16*)out)[idx] = (BF16)v;
            } else if (MODE == 1) {
                const float t2 = v + 0.044715f * v * v * v;
                const float s = 1.0f / (1.0f + __expf(-1.5957691216057308f * t2));
                ((BF16*)out)[idx] = (BF16)(v * s);
            } else {
                ((float*)out)[idx] = resid[idx] + v;
            }
        }
}

// ------------------------- causal flash attention ----------------------------
// 512 uniform blocks: block = (pair, bh), qb = pair then 31-pair (33 tiles).
// Double-buffered K/V staging, counted vmcnt(8). XCD-chunked mapping.
__global__ __launch_bounds__(256) void attn(const BF16* __restrict__ qkv,
                                            const BF16* __restrict__ vT,
                                            const float* __restrict__ x,
                                            float* __restrict__ x2) {
    __shared__ BF16 Ks[2][64 * 128];   // [key][d], swizzled rows (256 B)
    __shared__ BF16 Vs[2][128 * 64];   // [d][key], swizzled rows (128 B)
    __shared__ BF16 Ps[4][16 * 72];    // per-wave P [q][key], pad 64->72
    const int tid = threadIdx.x, l = tid & 63, w = tid >> 6;
    const int g = l >> 4, c = l & 15;
    const int bid = (int)blockIdx.x;
    const int wg = (bid & 7) * 64 + (bid >> 3);   // XCD chunking
    const int pair = wg & 15, bh = wg >> 4;
    const int b = bh >> 4, h = bh & 15;
    const int xr = (c & 7) << 4;

    const BF16* qbase = qkv + (size_t)b * 2048 * 6144 + h * 128;
    const char* kbase = (const char*)(qbase + 2048);
    const char* vbase = (const char*)(vT + (size_t)bh * 128 * 2048);

    auto STAGE = [&](int bb, int k0) {
        #pragma unroll
        for (int s = 0; s < 4; ++s) {
            const int rK = (w * 4 + s) * 4 + (l >> 4);
            const int cK = ((l & 15) * 16) ^ ((rK & 7) << 4);
            gld_lds16(kbase + (size_t)(k0 + rK) * 12288 + cK,
                      &Ks[bb][(w * 4 + s) * 512]);
            const int rV = (w * 4 + s) * 8 + (l >> 3);
            const int cV = ((l & 7) * 16) ^ ((rV & 7) << 4);
            gld_lds16(vbase + (size_t)rV * 4096 + (size_t)k0 * 2 + cV,
                      &Vs[bb][(w * 4 + s) * 512]);
        }
    };

    const float scale = 0.08838834764831845f;  // 1/sqrt(128)

    #pragma unroll 1
    for (int seg = 0; seg < 2; ++seg) {
        const int qb = seg ? 31 - pair : pair;
        const int q0 = qb * 64;

        bf16x8 qf[4];
        {
            const BF16* qrow = qbase + (size_t)(q0 + w * 16 + c) * 6144 + g * 8;
            #pragma unroll
            for (int kc = 0; kc < 4; kc++)
                qf[kc] = *(const bf16x8*)(qrow + kc * 32);
        }
        float m[4]    = {-1e30f, -1e30f, -1e30f, -1e30f};
        float lsum[4] = {0.f, 0.f, 0.f, 0.f};
        f32x4 O[8] = {};

        STAGE(0, 0);
        #pragma unroll 1
        for (int kt = 0; kt <= qb; ++kt) {
            if (kt < qb) { STAGE((kt + 1) & 1, (kt + 1) * 64); vmwait<8>(); }
            else vmwait<0>();
            __builtin_amdgcn_s_barrier();
            __builtin_amdgcn_sched_barrier(0);
            const char* KsB = (const char*)Ks[kt & 1];
            const char* VsB = (const char*)Vs[kt & 1];

            f32x4 s4[4] = {};
            #pragma unroll
            for (int ni = 0; ni < 4; ni++)
                #pragma unroll
                for (int kc = 0; kc < 4; kc++) {
                    const bf16x8 kf = *(const bf16x8*)(KsB +
                        (ni * 16 + c) * 256 + ((kc * 64 + g * 16) ^ xr));
                    s4[ni] = __builtin_amdgcn_mfma_f32_16x16x32_bf16(
                        qf[kc], kf, s4[ni], 0, 0, 0);
                }

            const bool maskt = (kt == qb);
            float sv[4][4];
            #pragma unroll
            for (int ni = 0; ni < 4; ni++)
                #pragma unroll
                for (int j = 0; j < 4; j++) {
                    const float v = s4[ni][j] * scale;
                    sv[ni][j] = (!maskt || (ni * 16 + c <= w * 16 + g * 4 + j))
                              ? v : -1e30f;
                }

            float sf[4];
            #pragma unroll
            for (int j = 0; j < 4; j++) {
                float tm = fmaxf(fmaxf(sv[0][j], sv[1][j]),
                                 fmaxf(sv[2][j], sv[3][j]));
                tm = fmaxf(tm, __shfl_xor(tm, 1));
                tm = fmaxf(tm, __shfl_xor(tm, 2));
                tm = fmaxf(tm, __shfl_xor(tm, 4));
                tm = fmaxf(tm, __shfl_xor(tm, 8));
                const float mn = fmaxf(m[j], tm);
                sf[j] = __expf(m[j] - mn);
                m[j] = mn;
            }

            float rs[4] = {0.f, 0.f, 0.f, 0.f};
            #pragma unroll
            for (int ni = 0; ni < 4; ni++)
                #pragma unroll
                for (int j = 0; j < 4; j++) {
                    const float p = __expf(sv[ni][j] - m[j]);
                    rs[j] += p;
                    Ps[w][(g * 4 + j) * 72 + ni * 16 + c] = (BF16)p;
                }
            #pragma unroll
            for (int j = 0; j < 4; j++) {
                float t = rs[j];
                t += __shfl_xor(t, 1);
                t += __shfl_xor(t, 2);
                t += __shfl_xor(t, 4);
                t += __shfl_xor(t, 8);
                lsum[j] = lsum[j] * sf[j] + t;
            }
            #pragma unroll
            for (int dn = 0; dn < 8; dn++)
                #pragma unroll
                for (int j = 0; j < 4; j++) O[dn][j] *= sf[j];

            bf16x8 pa[2];
            #pragma unroll
            for (int ks = 0; ks < 2; ks++)
                pa[ks] = *(const bf16x8*)((const char*)Ps[w] +
                             c * 144 + ks * 64 + g * 16);
            #pragma unroll
            for (int dn = 0; dn < 8; dn++)
                #pragma unroll
                for (int ks = 0; ks < 2; ks++) {
                    const bf16x8 vf = *(const bf16x8*)(VsB +
                        (dn * 16 + c) * 128 + ((ks * 64 + g * 16) ^ xr));
                    O[dn] = __builtin_amdgcn_mfma_f32_16x16x32_bf16(
                        pa[ks], vf, O[dn], 0, 0, 0);
                }
            __builtin_amdgcn_s_barrier();
            __builtin_amdgcn_sched_barrier(0);
        }

        float inv[4];
        #pragma unroll
        for (int j = 0; j < 4; j++) inv[j] = 1.0f / lsum[j];
        #pragma unroll
        for (int dn = 0; dn < 8; dn++)
            #pragma unroll
            for (int j = 0; j < 4; j++) {
                const int t   = q0 + w * 16 + g * 4 + j;
                const int col = h * 128 + dn * 16 + c;
                const size_t idx = ((size_t)b * 2048 + t) * 2048 + col;
                x2[idx] = x[idx] + O[dn][j] * inv[j];
            }
    }
}

// -----------------------------------------------------------------------------
extern "C" void kernel_launch(void* const* d_in, const int* in_sizes, int n_in,
                              void* d_out, int out_size, void* d_ws, size_t ws_size,
                              hipStream_t stream) {
    const float* x     = (const float*)d_in[0];
    const float* w_qkv = (const float*)d_in[1];
    const float* w1    = (const float*)d_in[2];
    const float* w2    = (const float*)d_in[3];
    const float* ln_w  = (const float*)d_in[4];
    float* out = (float*)d_out;

    char* ws = (char*)d_ws;
    BF16* h_buf = (BF16*)ws;  ws += (size_t)4096 * 2048 * 2;
    BF16* qkvb  = (BF16*)ws;  ws += (size_t)4096 * 6144 * 2;
    BF16* vTb   = (BF16*)ws;  ws += (size_t)32 * 128 * 2048 * 2;
    BF16* wqkvT = (BF16*)ws;  ws += (size_t)6144 * 2048 * 2;
    BF16* w1T   = (BF16*)ws;  ws += (size_t)8192 * 2048 * 2;
    BF16* w2T   = (BF16*)ws;  ws += (size_t)2048 * 8192 * 2;
    BF16* mlp1  = (BF16*)ws;  ws += (size_t)4096 * 8192 * 2;

    hipFuncSetAttribute((const void*)&gemmN<0, 256>,
                        hipFuncAttributeMaxDynamicSharedMemorySize, 131072);
    hipFuncSetAttribute((const void*)&gemmN<1, 256>,
                        hipFuncAttributeMaxDynamicSharedMemorySize, 131072);
    hipFuncSetAttribute((const void*)&gemmN<2, 128>,
                        hipFuncAttributeMaxDynamicSharedMemorySize, 98304);

    // ---- attention branch ----
    lnorm<<<4096, 256, 0, stream>>>(x, ln_w, h_buf);
    wtrans<<<dim3(192, 64), dim3(32, 8), 0, stream>>>(w_qkv, wqkvT, 2048, 6144);
    gemmN<0, 256><<<384, 512, 131072, stream>>>(
        h_buf, wqkvT, qkvb, nullptr, 4096, 6144, 2048);
    vtrans<<<dim3(64, 4, 32), dim3(32, 8), 0, stream>>>(qkvb, vTb);
    attn<<<512, 256, 0, stream>>>(qkvb, vTb, x, out);  // out = x2

    // ---- MLP branch ----
    lnorm<<<4096, 256, 0, stream>>>(out, ln_w, h_buf);
    wtrans<<<dim3(256, 64), dim3(32, 8), 0, stream>>>(w1, w1T, 2048, 8192);
    gemmN<1, 256><<<512, 512, 131072, stream>>>(
        h_buf, w1T, mlp1, nullptr, 4096, 8192, 2048);
    wtrans<<<dim3(64, 256), dim3(32, 8), 0, stream>>>(w2, w2T, 8192, 2048);
    gemmN<2, 128><<<256, 512, 98304, stream>>>(
        mlp1, w2T, out, out, 4096, 2048, 8192);
}